// Round 3
// baseline (1473.796 us; speedup 1.0000x reference)
//
#include <hip/hip_runtime.h>
#include <math.h>

// ---------------------------------------------------------------------------
// GIN multi-graph model, MI355X (gfx950) — round 3
//  - fused gather+MLP layer kernel (weights pinned in VGPRs, 16-deep MLP)
//  - ranged scatter (4 dst-range passes) to kill 16x write amplification
// ---------------------------------------------------------------------------

static __device__ __forceinline__ float rlf(float v, int k) {
    return __int_as_float(__builtin_amdgcn_readlane(__float_as_int(v), k));
}
static __device__ __forceinline__ int rli(int v, int k) {
    return __builtin_amdgcn_readlane(v, k);
}

// ---------------- CSR build ----------------

__global__ void k_hist(const int* __restrict__ dst, int* __restrict__ deg, int E) {
    int i = blockIdx.x * blockDim.x + threadIdx.x;
    int stride = gridDim.x * blockDim.x;
    for (; i < E; i += stride) atomicAdd(&deg[dst[i]], 1);
}

#define SCAN_B 512

__global__ void k_scan1(const int* __restrict__ deg, int* __restrict__ ex,
                        int* __restrict__ bsum, int n) {
    __shared__ int s[SCAN_B];
    int t = threadIdx.x;
    int i = blockIdx.x * SCAN_B + t;
    int v = (i < n) ? deg[i] : 0;
    s[t] = v;
    __syncthreads();
    for (int off = 1; off < SCAN_B; off <<= 1) {
        int tv = (t >= off) ? s[t - off] : 0;
        __syncthreads();
        s[t] += tv;
        __syncthreads();
    }
    if (i < n) ex[i] = s[t] - v;
    if (t == SCAN_B - 1) bsum[blockIdx.x] = s[t];
}

__global__ void k_scan2(int* __restrict__ bsum, int nb) {
    __shared__ int s[SCAN_B];
    int t = threadIdx.x;
    int v = (t < nb) ? bsum[t] : 0;
    s[t] = v;
    __syncthreads();
    for (int off = 1; off < SCAN_B; off <<= 1) {
        int tv = (t >= off) ? s[t - off] : 0;
        __syncthreads();
        s[t] += tv;
        __syncthreads();
    }
    if (t < nb) bsum[t] = s[t] - v;
}

__global__ void k_scan3(int* __restrict__ ex, const int* __restrict__ bsum,
                        int n, int E) {
    int i = blockIdx.x * SCAN_B + threadIdx.x;
    if (i < n) ex[i] += bsum[blockIdx.x];
    if (blockIdx.x == 0 && threadIdx.x == 0) ex[n] = E;
}

// ranged scatter: only edges whose dst lies in [lo,hi) — keeps the active
// csr region L2-resident so 64B lines fill before eviction.
__global__ void k_scatter_r(const int* __restrict__ src, const int* __restrict__ dst,
                            const int* __restrict__ row_start, int* __restrict__ cur,
                            int* __restrict__ csr, int E, int lo, int hi) {
    int i = blockIdx.x * blockDim.x + threadIdx.x;
    int stride = gridDim.x * blockDim.x;
    for (; i < E; i += stride) {
        int d = dst[i];
        if (d >= lo && d < hi) {
            int p = atomicAdd(&cur[d], 1);
            csr[row_start[d] + p] = src[i];
        }
    }
}

__global__ void k_gstart(const int* __restrict__ batch, int* __restrict__ gs,
                         int n, int G) {
    int g = blockIdx.x * blockDim.x + threadIdx.x;
    if (g > G) return;
    if (g == G) { gs[G] = n; return; }
    int lo = 0, hi = n;
    while (lo < hi) {
        int mid = (lo + hi) >> 1;
        if (batch[mid] < g) lo = mid + 1; else hi = mid;
    }
    gs[g] = lo;
}

// weight transpose: Wt[l][j][k] = W[l][k][j]
__global__ void k_wt(const float* __restrict__ W, float* __restrict__ Wt, int total) {
    int i = blockIdx.x * blockDim.x + threadIdx.x;
    if (i >= total) return;
    int l = i >> 12, r = i & 4095, j = r >> 6, k = r & 63;
    Wt[(l << 12) + (j << 6) + k] = W[(l << 12) + (k << 6) + j];
}

// ------------- fused layer: gather -> GEMM1 -> BN -> ReLU -> GEMM2 -> ReLU --

__global__ __launch_bounds__(256, 2) void k_layer(
    const float* __restrict__ x, const int* __restrict__ row_start,
    const int* __restrict__ csr,
    const float* __restrict__ Wt1, const float* __restrict__ b1,
    const float* __restrict__ gamma, const float* __restrict__ beta,
    const float* __restrict__ mean, const float* __restrict__ var,
    const float* __restrict__ Wt2, const float* __restrict__ b2,
    float* __restrict__ xout, int n)
{
    int lane = threadIdx.x & 63;
    int wid = (blockIdx.x * blockDim.x + threadIdx.x) >> 6;
    int nw = (gridDim.x * blockDim.x) >> 6;

    // lane's output column of W1/W2 (transposed layout): 16+16 float4 loads
    float4 w1v[16], w2v[16];
    const float4* W1p = (const float4*)Wt1 + (size_t)lane * 16;
    const float4* W2p = (const float4*)Wt2 + (size_t)lane * 16;
#pragma unroll
    for (int q = 0; q < 16; ++q) w1v[q] = W1p[q];
#pragma unroll
    for (int q = 0; q < 16; ++q) w2v[q] = W2p[q];
    // pin in VGPRs: compiler cannot re-sink the loads into the node loop
#pragma unroll
    for (int q = 0; q < 16; ++q) {
        asm volatile("" : "+v"(w1v[q].x), "+v"(w1v[q].y), "+v"(w1v[q].z), "+v"(w1v[q].w));
        asm volatile("" : "+v"(w2v[q].x), "+v"(w2v[q].y), "+v"(w2v[q].z), "+v"(w2v[q].w));
    }
    const float* w1 = (const float*)w1v;
    const float* w2 = (const float*)w2v;

    float bias1 = b1[lane];
    float sc = gamma[lane] * rsqrtf(var[lane] + 1e-5f);
    float sh = beta[lane] - mean[lane] * sc;
    float bias2 = b2[lane];

    for (int node = wid; node < n; node += nw) {
        // ---- gather: acc = x[node] + sum of neighbor rows (16-deep MLP) ----
        float acc = x[(size_t)node * 64 + lane];
        int s0 = row_start[node], s1 = row_start[node + 1];
        int j = s0;
        for (; j + 16 <= s1; j += 16) {
            int idx = csr[j + (lane & 15)];          // 16 indices, one 64B line
            float t0 = 0.f, t1 = 0.f, t2 = 0.f, t3 = 0.f;
#pragma unroll
            for (int u = 0; u < 16; u += 4) {        // 16 independent row loads
                float a0 = x[(size_t)rli(idx, u + 0) * 64 + lane];
                float a1 = x[(size_t)rli(idx, u + 1) * 64 + lane];
                float a2 = x[(size_t)rli(idx, u + 2) * 64 + lane];
                float a3 = x[(size_t)rli(idx, u + 3) * 64 + lane];
                t0 += a0; t1 += a1; t2 += a2; t3 += a3;
            }
            acc += (t0 + t1) + (t2 + t3);
        }
        int cnt = s1 - j;                            // tail < 16 (clamped batch)
        if (cnt) {
            int idx = csr[j + (lane & 15)];
            float s = 0.f;
#pragma unroll
            for (int u = 0; u < 16; ++u) {
                int jc = (u < cnt) ? u : 0;          // uniform clamp
                float a = x[(size_t)rli(idx, jc) * 64 + lane];
                s += (u < cnt) ? a : 0.f;
            }
            acc += s;
        }
        // ---- GEMM1 (4 chains) + BN + ReLU ----
        float h0 = bias1, h1 = 0.f, h2 = 0.f, h3 = 0.f;
#pragma unroll
        for (int k = 0; k < 64; k += 4) {
            h0 += rlf(acc, k + 0) * w1[k + 0];
            h1 += rlf(acc, k + 1) * w1[k + 1];
            h2 += rlf(acc, k + 2) * w1[k + 2];
            h3 += rlf(acc, k + 3) * w1[k + 3];
        }
        float h = fmaxf(((h0 + h1) + (h2 + h3)) * sc + sh, 0.f);
        // ---- GEMM2 (4 chains) + ReLU ----
        float o0 = bias2, o1 = 0.f, o2 = 0.f, o3 = 0.f;
#pragma unroll
        for (int k = 0; k < 64; k += 4) {
            o0 += rlf(h, k + 0) * w2[k + 0];
            o1 += rlf(h, k + 1) * w2[k + 1];
            o2 += rlf(h, k + 2) * w2[k + 2];
            o3 += rlf(h, k + 3) * w2[k + 3];
        }
        xout[(size_t)node * 64 + lane] = fmaxf((o0 + o1) + (o2 + o3), 0.f);
    }
}

// ---------------- per-graph pooling ----------------

__global__ __launch_bounds__(256) void k_pool(const float* __restrict__ x,
                                              const int* __restrict__ gs,
                                              float* __restrict__ pooled,
                                              int G, int l, int lh) {
    int lane = threadIdx.x & 63;
    int wid = (blockIdx.x * blockDim.x + threadIdx.x) >> 6;
    if (wid >= G) return;
    int s0 = gs[wid], s1 = gs[wid + 1];
    float a0 = 0, a1 = 0, a2 = 0, a3 = 0;
    int nd = s0;
    for (; nd + 4 <= s1; nd += 4) {
        a0 += x[(size_t)(nd + 0) * 64 + lane];
        a1 += x[(size_t)(nd + 1) * 64 + lane];
        a2 += x[(size_t)(nd + 2) * 64 + lane];
        a3 += x[(size_t)(nd + 3) * 64 + lane];
    }
    for (; nd < s1; ++nd) a0 += x[(size_t)nd * 64 + lane];
    pooled[(size_t)wid * lh + l * 64 + lane] = (a0 + a1) + (a2 + a3);
}

// ---------------- FC head ----------------

__global__ __launch_bounds__(256) void k_fc(
    const float* __restrict__ pooled, const int* __restrict__ acid,
    const float* __restrict__ conc, const float* __restrict__ emb_acid,
    const float* __restrict__ emb_conc, const float* __restrict__ fc1W,
    const float* __restrict__ fc1b, const float* __restrict__ fc2W,
    const float* __restrict__ fc2b, float* __restrict__ out, int G, int lh)
{
    __shared__ float sf[4][448];
    int lane = threadIdx.x & 63;
    int w = threadIdx.x >> 6;
    int g = blockIdx.x * 4 + w;
    int fcin = lh + 256;
    if (g < G) {
        const float* pr = pooled + (size_t)g * lh;
        for (int c = lane; c < lh; c += 64) sf[w][c] = pr[c];
        const float* ea = emb_acid + acid[g] * 128;
        int ci = (conc[g] == 0.5f) ? 0 : 1;
        const float* ec = emb_conc + ci * 128;
        sf[w][lh + lane] = ea[lane];
        sf[w][lh + 64 + lane] = ea[lane + 64];
        sf[w][lh + 128 + lane] = ec[lane];
        sf[w][lh + 192 + lane] = ec[lane + 64];
    }
    __syncthreads();
    if (g >= G) return;
    float h0 = fc1b[lane], h1 = 0.f;
    for (int k = 0; k + 2 <= fcin; k += 2) {
        h0 += sf[w][k] * fc1W[(size_t)k * 64 + lane];
        h1 += sf[w][k + 1] * fc1W[(size_t)(k + 1) * 64 + lane];
    }
    float h = fmaxf(h0 + h1, 0.f);
    float p0 = h * fc2W[lane * 2 + 0];
    float p1 = h * fc2W[lane * 2 + 1];
    for (int off = 32; off; off >>= 1) {
        p0 += __shfl_xor(p0, off, 64);
        p1 += __shfl_xor(p1, off, 64);
    }
    if (lane == 0) {
        out[g * 2 + 0] = 1.0f / (1.0f + expf(-(p0 + fc2b[0])));
        out[g * 2 + 1] = 1.0f / (1.0f + expf(-(p1 + fc2b[1])));
    }
}

// ---------------- launch ----------------

extern "C" void kernel_launch(void* const* d_in, const int* in_sizes, int n_in,
                              void* d_out, int out_size, void* d_ws, size_t ws_size,
                              hipStream_t stream)
{
    const float* x_a      = (const float*)d_in[0];
    const int*   ei       = (const int*)d_in[1];
    const int*   batch    = (const int*)d_in[2];
    const int*   acid     = (const int*)d_in[3];
    const float* conc     = (const float*)d_in[4];
    const float* W1s      = (const float*)d_in[6];
    const float* b1s      = (const float*)d_in[7];
    const float* gammas   = (const float*)d_in[8];
    const float* betas    = (const float*)d_in[9];
    const float* bn_means = (const float*)d_in[10];
    const float* bn_vars  = (const float*)d_in[11];
    const float* W2s      = (const float*)d_in[12];
    const float* b2s      = (const float*)d_in[13];
    const float* emb_acid = (const float*)d_in[14];
    const float* emb_conc = (const float*)d_in[15];
    const float* fc1W     = (const float*)d_in[16];
    const float* fc1b     = (const float*)d_in[17];
    const float* fc2W     = (const float*)d_in[18];
    const float* fc2b     = (const float*)d_in[19];

    const int N = in_sizes[0] / 64;
    const int E = in_sizes[1] / 2;
    const int G = in_sizes[3];
    const int L = in_sizes[6] / (64 * 64);
    const int LH = 64 * L;

    char* ws = (char*)d_ws;
    size_t off = 0;
    auto alloc = [&](size_t bytes) -> void* {
        void* p = ws + off;
        off += (bytes + 255) & ~(size_t)255;
        return p;
    };
    float* buf0      = (float*)alloc((size_t)N * 64 * 4);
    float* buf1      = (float*)alloc((size_t)N * 64 * 4);
    float* pooled    = (float*)alloc((size_t)G * LH * 4);
    int*   row_start = (int*)alloc((size_t)(N + 1) * 4);
    int*   deg       = (int*)alloc((size_t)N * 4);      // reused as cursor
    int*   csr       = (int*)alloc((size_t)E * 4);
    int*   bsum      = (int*)alloc(4096);
    int*   gs        = (int*)alloc((size_t)(G + 1) * 4);
    float* Wt1       = (float*)alloc((size_t)L * 4096 * 4);
    float* Wt2       = (float*)alloc((size_t)L * 4096 * 4);

    const int* srcv = ei;
    const int* dstv = ei + E;

    // CSR build (reused by all layers)
    hipMemsetAsync(deg, 0, (size_t)N * 4, stream);
    k_hist<<<4096, 256, 0, stream>>>(dstv, deg, E);
    int nb = (N + SCAN_B - 1) / SCAN_B;
    k_scan1<<<nb, SCAN_B, 0, stream>>>(deg, row_start, bsum, N);
    k_scan2<<<1, SCAN_B, 0, stream>>>(bsum, nb);
    k_scan3<<<nb, SCAN_B, 0, stream>>>(row_start, bsum, N, E);
    hipMemsetAsync(deg, 0, (size_t)N * 4, stream);
    const int NPASS = 4;
    for (int p = 0; p < NPASS; ++p) {
        int lo = (int)((long long)N * p / NPASS);
        int hi = (int)((long long)N * (p + 1) / NPASS);
        k_scatter_r<<<4096, 256, 0, stream>>>(srcv, dstv, row_start, deg, csr, E, lo, hi);
    }
    k_gstart<<<(G + 256) / 256, 256, 0, stream>>>(batch, gs, N, G);

    // weight transposes (lane-major columns)
    int wtot = L * 4096;
    k_wt<<<(wtot + 255) / 256, 256, 0, stream>>>(W1s, Wt1, wtot);
    k_wt<<<(wtot + 255) / 256, 256, 0, stream>>>(W2s, Wt2, wtot);

    // GIN layers: fused gather+MLP -> pool
    const float* xin = x_a;
    float* bufs[2] = {buf0, buf1};
    for (int l = 0; l < L; ++l) {
        float* xb = bufs[l & 1];
        k_layer<<<2048, 256, 0, stream>>>(
            xin, row_start, csr,
            Wt1 + (size_t)l * 4096, b1s + l * 64,
            gammas + l * 64, betas + l * 64,
            bn_means + l * 64, bn_vars + l * 64,
            Wt2 + (size_t)l * 4096, b2s + l * 64,
            xb, N);
        k_pool<<<(G + 3) / 4, 256, 0, stream>>>(xb, gs, pooled, G, l, LH);
        xin = xb;
    }

    // FC head
    k_fc<<<(G + 3) / 4, 256, 0, stream>>>(pooled, acid, conc, emb_acid, emb_conc,
                                          fc1W, fc1b, fc2W, fc2b,
                                          (float*)d_out, G, LH);
}

// Round 4
// 1201.113 us; speedup vs baseline: 1.2270x; 1.2270x over previous
//
#include <hip/hip_runtime.h>
#include <math.h>

// ---------------------------------------------------------------------------
// GIN multi-graph model, MI355X (gfx950) — round 4
// Split kernels (gather = latency regime, gemm = VALU regime).
// k_gemm: weights truly pinned in VGPRs (component access, no address taken),
//         software-pipelined node loop.
// ---------------------------------------------------------------------------

static __device__ __forceinline__ float rlf(float v, int k) {
    return __int_as_float(__builtin_amdgcn_readlane(__float_as_int(v), k));
}
static __device__ __forceinline__ int rli(int v, int k) {
    return __builtin_amdgcn_readlane(v, k);
}

// ---------------- CSR build ----------------

__global__ void k_hist(const int* __restrict__ dst, int* __restrict__ deg, int E) {
    int i = blockIdx.x * blockDim.x + threadIdx.x;
    int stride = gridDim.x * blockDim.x;
    for (; i < E; i += stride) atomicAdd(&deg[dst[i]], 1);
}

#define SCAN_B 512

__global__ void k_scan1(const int* __restrict__ deg, int* __restrict__ ex,
                        int* __restrict__ bsum, int n) {
    __shared__ int s[SCAN_B];
    int t = threadIdx.x;
    int i = blockIdx.x * SCAN_B + t;
    int v = (i < n) ? deg[i] : 0;
    s[t] = v;
    __syncthreads();
    for (int off = 1; off < SCAN_B; off <<= 1) {
        int tv = (t >= off) ? s[t - off] : 0;
        __syncthreads();
        s[t] += tv;
        __syncthreads();
    }
    if (i < n) ex[i] = s[t] - v;
    if (t == SCAN_B - 1) bsum[blockIdx.x] = s[t];
}

__global__ void k_scan2(int* __restrict__ bsum, int nb) {
    __shared__ int s[SCAN_B];
    int t = threadIdx.x;
    int v = (t < nb) ? bsum[t] : 0;
    s[t] = v;
    __syncthreads();
    for (int off = 1; off < SCAN_B; off <<= 1) {
        int tv = (t >= off) ? s[t - off] : 0;
        __syncthreads();
        s[t] += tv;
        __syncthreads();
    }
    if (t < nb) bsum[t] = s[t] - v;
}

__global__ void k_scan3(int* __restrict__ ex, const int* __restrict__ bsum,
                        int n, int E) {
    int i = blockIdx.x * SCAN_B + threadIdx.x;
    if (i < n) ex[i] += bsum[blockIdx.x];
    if (blockIdx.x == 0 && threadIdx.x == 0) ex[n] = E;
}

__global__ void k_scatter(const int* __restrict__ src, const int* __restrict__ dst,
                          const int* __restrict__ row_start, int* __restrict__ cur,
                          int* __restrict__ csr, int E) {
    int i = blockIdx.x * blockDim.x + threadIdx.x;
    int stride = gridDim.x * blockDim.x;
    for (; i < E; i += stride) {
        int d = dst[i];
        int p = atomicAdd(&cur[d], 1);
        csr[row_start[d] + p] = src[i];
    }
}

__global__ void k_gstart(const int* __restrict__ batch, int* __restrict__ gs,
                         int n, int G) {
    int g = blockIdx.x * blockDim.x + threadIdx.x;
    if (g > G) return;
    if (g == G) { gs[G] = n; return; }
    int lo = 0, hi = n;
    while (lo < hi) {
        int mid = (lo + hi) >> 1;
        if (batch[mid] < g) lo = mid + 1; else hi = mid;
    }
    gs[g] = lo;
}

// weight transpose: Wt[l][j][k] = W[l][k][j]  (lane j's column contiguous)
__global__ void k_wt(const float* __restrict__ W, float* __restrict__ Wt, int total) {
    int i = blockIdx.x * blockDim.x + threadIdx.x;
    if (i >= total) return;
    int l = i >> 12, r = i & 4095, j = r >> 6, k = r & 63;
    Wt[(l << 12) + (j << 6) + k] = W[(l << 12) + (k << 6) + j];
}

// ---------------- gather: agg[n] = x[n] + sum_{j in CSR row n} x[j] ----------

__global__ __launch_bounds__(256) void k_gather(
    const float* __restrict__ x, const int* __restrict__ row_start,
    const int* __restrict__ csr, float* __restrict__ agg, int n)
{
    int lane = threadIdx.x & 63;
    int wid = (blockIdx.x * blockDim.x + threadIdx.x) >> 6;
    int nw = (gridDim.x * blockDim.x) >> 6;
    for (int node = wid; node < n; node += nw) {
        float acc = x[(size_t)node * 64 + lane];
        int s0 = row_start[node], s1 = row_start[node + 1];
        int j = s0;
        for (; j + 16 <= s1; j += 16) {
            int idx = csr[j + (lane & 15)];          // 16 indices, one 64B line
            float a[16];
#pragma unroll
            for (int u = 0; u < 16; ++u)             // 16 independent row loads
                a[u] = x[(size_t)rli(idx, u) * 64 + lane];
            float t0 = (a[0] + a[1]) + (a[2] + a[3]);
            float t1 = (a[4] + a[5]) + (a[6] + a[7]);
            float t2 = (a[8] + a[9]) + (a[10] + a[11]);
            float t3 = (a[12] + a[13]) + (a[14] + a[15]);
            acc += (t0 + t1) + (t2 + t3);
        }
        int cnt = s1 - j;                            // tail < 16
        if (cnt) {
            int idx = csr[j + (lane & 15)];
            float s = 0.f;
#pragma unroll
            for (int u = 0; u < 16; ++u) {
                int jc = (u < cnt) ? u : 0;          // uniform clamp
                float a = x[(size_t)rli(idx, jc) * 64 + lane];
                s += (u < cnt) ? a : 0.f;
            }
            acc += s;
        }
        agg[(size_t)node * 64 + lane] = acc;
    }
}

// ------- GEMM1 + BN + ReLU + GEMM2 + ReLU, in-place, weights in VGPRs -------

__global__ __launch_bounds__(256, 2) void k_gemm(
    float* __restrict__ xb,                       // in: agg, out: layer output
    const float* __restrict__ Wt1, const float* __restrict__ b1,
    const float* __restrict__ gamma, const float* __restrict__ beta,
    const float* __restrict__ mean, const float* __restrict__ var,
    const float* __restrict__ Wt2, const float* __restrict__ b2, int n)
{
    int lane = threadIdx.x & 63;
    int wid = (blockIdx.x * blockDim.x + threadIdx.x) >> 6;
    int nw = (gridDim.x * blockDim.x) >> 6;

    // lane's output column of W1/W2: 16+16 contiguous float4 loads
    float4 w1v[16], w2v[16];
    const float4* W1p = (const float4*)Wt1 + (size_t)lane * 16;
    const float4* W2p = (const float4*)Wt2 + (size_t)lane * 16;
#pragma unroll
    for (int q = 0; q < 16; ++q) w1v[q] = W1p[q];
#pragma unroll
    for (int q = 0; q < 16; ++q) w2v[q] = W2p[q];
    // pin values in VGPRs (register constraints only — NO address taken)
#pragma unroll
    for (int q = 0; q < 16; ++q) {
        asm volatile("" : "+v"(w1v[q].x), "+v"(w1v[q].y), "+v"(w1v[q].z), "+v"(w1v[q].w));
        asm volatile("" : "+v"(w2v[q].x), "+v"(w2v[q].y), "+v"(w2v[q].z), "+v"(w2v[q].w));
    }

    float bias1 = b1[lane];
    float sc = gamma[lane] * rsqrtf(var[lane] + 1e-5f);
    float sh = beta[lane] - mean[lane] * sc;
    float bias2 = b2[lane];

    int node = wid;
    float a = (node < n) ? xb[(size_t)node * 64 + lane] : 0.f;
    while (node < n) {
        int nxt = node + nw;
        float anx = (nxt < n) ? xb[(size_t)nxt * 64 + lane] : 0.f;  // prefetch

        float h0 = bias1, h1 = 0.f, h2 = 0.f, h3 = 0.f;
#pragma unroll
        for (int q = 0; q < 16; ++q) {
            h0 += rlf(a, 4 * q + 0) * w1v[q].x;
            h1 += rlf(a, 4 * q + 1) * w1v[q].y;
            h2 += rlf(a, 4 * q + 2) * w1v[q].z;
            h3 += rlf(a, 4 * q + 3) * w1v[q].w;
        }
        float h = fmaxf(((h0 + h1) + (h2 + h3)) * sc + sh, 0.f);

        float o0 = bias2, o1 = 0.f, o2 = 0.f, o3 = 0.f;
#pragma unroll
        for (int q = 0; q < 16; ++q) {
            o0 += rlf(h, 4 * q + 0) * w2v[q].x;
            o1 += rlf(h, 4 * q + 1) * w2v[q].y;
            o2 += rlf(h, 4 * q + 2) * w2v[q].z;
            o3 += rlf(h, 4 * q + 3) * w2v[q].w;
        }
        xb[(size_t)node * 64 + lane] = fmaxf((o0 + o1) + (o2 + o3), 0.f);

        node = nxt;
        a = anx;
    }
}

// ---------------- per-graph pooling ----------------

__global__ __launch_bounds__(256) void k_pool(const float* __restrict__ x,
                                              const int* __restrict__ gs,
                                              float* __restrict__ pooled,
                                              int G, int l, int lh) {
    int lane = threadIdx.x & 63;
    int wid = (blockIdx.x * blockDim.x + threadIdx.x) >> 6;
    if (wid >= G) return;
    int s0 = gs[wid], s1 = gs[wid + 1];
    float a0 = 0, a1 = 0, a2 = 0, a3 = 0;
    int nd = s0;
    for (; nd + 4 <= s1; nd += 4) {
        a0 += x[(size_t)(nd + 0) * 64 + lane];
        a1 += x[(size_t)(nd + 1) * 64 + lane];
        a2 += x[(size_t)(nd + 2) * 64 + lane];
        a3 += x[(size_t)(nd + 3) * 64 + lane];
    }
    for (; nd < s1; ++nd) a0 += x[(size_t)nd * 64 + lane];
    pooled[(size_t)wid * lh + l * 64 + lane] = (a0 + a1) + (a2 + a3);
}

// ---------------- FC head ----------------

__global__ __launch_bounds__(256) void k_fc(
    const float* __restrict__ pooled, const int* __restrict__ acid,
    const float* __restrict__ conc, const float* __restrict__ emb_acid,
    const float* __restrict__ emb_conc, const float* __restrict__ fc1W,
    const float* __restrict__ fc1b, const float* __restrict__ fc2W,
    const float* __restrict__ fc2b, float* __restrict__ out, int G, int lh)
{
    __shared__ float sf[4][448];
    int lane = threadIdx.x & 63;
    int w = threadIdx.x >> 6;
    int g = blockIdx.x * 4 + w;
    int fcin = lh + 256;
    if (g < G) {
        const float* pr = pooled + (size_t)g * lh;
        for (int c = lane; c < lh; c += 64) sf[w][c] = pr[c];
        const float* ea = emb_acid + acid[g] * 128;
        int ci = (conc[g] == 0.5f) ? 0 : 1;
        const float* ec = emb_conc + ci * 128;
        sf[w][lh + lane] = ea[lane];
        sf[w][lh + 64 + lane] = ea[lane + 64];
        sf[w][lh + 128 + lane] = ec[lane];
        sf[w][lh + 192 + lane] = ec[lane + 64];
    }
    __syncthreads();
    if (g >= G) return;
    float h0 = fc1b[lane], h1 = 0.f;
    for (int k = 0; k + 2 <= fcin; k += 2) {
        h0 += sf[w][k] * fc1W[(size_t)k * 64 + lane];
        h1 += sf[w][k + 1] * fc1W[(size_t)(k + 1) * 64 + lane];
    }
    float h = fmaxf(h0 + h1, 0.f);
    float p0 = h * fc2W[lane * 2 + 0];
    float p1 = h * fc2W[lane * 2 + 1];
    for (int off = 32; off; off >>= 1) {
        p0 += __shfl_xor(p0, off, 64);
        p1 += __shfl_xor(p1, off, 64);
    }
    if (lane == 0) {
        out[g * 2 + 0] = 1.0f / (1.0f + expf(-(p0 + fc2b[0])));
        out[g * 2 + 1] = 1.0f / (1.0f + expf(-(p1 + fc2b[1])));
    }
}

// ---------------- launch ----------------

extern "C" void kernel_launch(void* const* d_in, const int* in_sizes, int n_in,
                              void* d_out, int out_size, void* d_ws, size_t ws_size,
                              hipStream_t stream)
{
    const float* x_a      = (const float*)d_in[0];
    const int*   ei       = (const int*)d_in[1];
    const int*   batch    = (const int*)d_in[2];
    const int*   acid     = (const int*)d_in[3];
    const float* conc     = (const float*)d_in[4];
    const float* W1s      = (const float*)d_in[6];
    const float* b1s      = (const float*)d_in[7];
    const float* gammas   = (const float*)d_in[8];
    const float* betas    = (const float*)d_in[9];
    const float* bn_means = (const float*)d_in[10];
    const float* bn_vars  = (const float*)d_in[11];
    const float* W2s      = (const float*)d_in[12];
    const float* b2s      = (const float*)d_in[13];
    const float* emb_acid = (const float*)d_in[14];
    const float* emb_conc = (const float*)d_in[15];
    const float* fc1W     = (const float*)d_in[16];
    const float* fc1b     = (const float*)d_in[17];
    const float* fc2W     = (const float*)d_in[18];
    const float* fc2b     = (const float*)d_in[19];

    const int N = in_sizes[0] / 64;
    const int E = in_sizes[1] / 2;
    const int G = in_sizes[3];
    const int L = in_sizes[6] / (64 * 64);
    const int LH = 64 * L;

    char* ws = (char*)d_ws;
    size_t off = 0;
    auto alloc = [&](size_t bytes) -> void* {
        void* p = ws + off;
        off += (bytes + 255) & ~(size_t)255;
        return p;
    };
    float* buf0      = (float*)alloc((size_t)N * 64 * 4);
    float* buf1      = (float*)alloc((size_t)N * 64 * 4);
    float* pooled    = (float*)alloc((size_t)G * LH * 4);
    int*   row_start = (int*)alloc((size_t)(N + 1) * 4);
    int*   deg       = (int*)alloc((size_t)N * 4);      // reused as cursor
    int*   csr       = (int*)alloc((size_t)E * 4);
    int*   bsum      = (int*)alloc(4096);
    int*   gs        = (int*)alloc((size_t)(G + 1) * 4);
    float* Wt1       = (float*)alloc((size_t)L * 4096 * 4);
    float* Wt2       = (float*)alloc((size_t)L * 4096 * 4);

    const int* srcv = ei;
    const int* dstv = ei + E;

    // CSR build (reused by all layers)
    hipMemsetAsync(deg, 0, (size_t)N * 4, stream);
    k_hist<<<4096, 256, 0, stream>>>(dstv, deg, E);
    int nb = (N + SCAN_B - 1) / SCAN_B;
    k_scan1<<<nb, SCAN_B, 0, stream>>>(deg, row_start, bsum, N);
    k_scan2<<<1, SCAN_B, 0, stream>>>(bsum, nb);
    k_scan3<<<nb, SCAN_B, 0, stream>>>(row_start, bsum, N, E);
    hipMemsetAsync(deg, 0, (size_t)N * 4, stream);
    k_scatter<<<4096, 256, 0, stream>>>(srcv, dstv, row_start, deg, csr, E);
    k_gstart<<<(G + 256) / 256, 256, 0, stream>>>(batch, gs, N, G);

    // weight transposes (lane-major columns)
    int wtot = L * 4096;
    k_wt<<<(wtot + 255) / 256, 256, 0, stream>>>(W1s, Wt1, wtot);
    k_wt<<<(wtot + 255) / 256, 256, 0, stream>>>(W2s, Wt2, wtot);

    // GIN layers: gather -> in-place MLP -> pool
    const float* xin = x_a;
    float* bufs[2] = {buf0, buf1};
    for (int l = 0; l < L; ++l) {
        float* xb = bufs[l & 1];
        k_gather<<<4096, 256, 0, stream>>>(xin, row_start, csr, xb, N);
        k_gemm<<<2048, 256, 0, stream>>>(
            xb, Wt1 + (size_t)l * 4096, b1s + l * 64,
            gammas + l * 64, betas + l * 64,
            bn_means + l * 64, bn_vars + l * 64,
            Wt2 + (size_t)l * 4096, b2s + l * 64, N);
        k_pool<<<(G + 3) / 4, 256, 0, stream>>>(xb, gs, pooled, G, l, LH);
        xin = xb;
    }

    // FC head
    k_fc<<<(G + 3) / 4, 256, 0, stream>>>(pooled, acid, conc, emb_acid, emb_conc,
                                          fc1W, fc1b, fc2W, fc2b,
                                          (float*)d_out, G, LH);
}

// Round 5
// 1200.753 us; speedup vs baseline: 1.2274x; 1.0003x over previous
//
#include <hip/hip_runtime.h>
#include <math.h>

// ---------------------------------------------------------------------------
// GIN multi-graph model, MI355X (gfx950) — round 5
//  - k_gather: 4 rows per load instr (float4 lanes, 16 rows in flight,
//    cross-group shfl reduce) -> fewer issue slots, same MLP
//  - k_gemm_pool: wave-per-graph, 4 nodes per 1KB load, weights pinned in
//    VGPRs, graph pooling fused (kills k_pool + its 51MB/layer re-read)
// ---------------------------------------------------------------------------

static __device__ __forceinline__ float rlf(float v, int k) {
    return __int_as_float(__builtin_amdgcn_readlane(__float_as_int(v), k));
}

// ---------------- CSR build ----------------

__global__ void k_hist(const int* __restrict__ dst, int* __restrict__ deg, int E) {
    int i = blockIdx.x * blockDim.x + threadIdx.x;
    int stride = gridDim.x * blockDim.x;
    for (; i < E; i += stride) atomicAdd(&deg[dst[i]], 1);
}

#define SCAN_B 512

__global__ void k_scan1(const int* __restrict__ deg, int* __restrict__ ex,
                        int* __restrict__ bsum, int n) {
    __shared__ int s[SCAN_B];
    int t = threadIdx.x;
    int i = blockIdx.x * SCAN_B + t;
    int v = (i < n) ? deg[i] : 0;
    s[t] = v;
    __syncthreads();
    for (int off = 1; off < SCAN_B; off <<= 1) {
        int tv = (t >= off) ? s[t - off] : 0;
        __syncthreads();
        s[t] += tv;
        __syncthreads();
    }
    if (i < n) ex[i] = s[t] - v;
    if (t == SCAN_B - 1) bsum[blockIdx.x] = s[t];
}

__global__ void k_scan2(int* __restrict__ bsum, int nb) {
    __shared__ int s[SCAN_B];
    int t = threadIdx.x;
    int v = (t < nb) ? bsum[t] : 0;
    s[t] = v;
    __syncthreads();
    for (int off = 1; off < SCAN_B; off <<= 1) {
        int tv = (t >= off) ? s[t - off] : 0;
        __syncthreads();
        s[t] += tv;
        __syncthreads();
    }
    if (t < nb) bsum[t] = s[t] - v;
}

__global__ void k_scan3(int* __restrict__ ex, const int* __restrict__ bsum,
                        int n, int E) {
    int i = blockIdx.x * SCAN_B + threadIdx.x;
    if (i < n) ex[i] += bsum[blockIdx.x];
    if (blockIdx.x == 0 && threadIdx.x == 0) ex[n] = E;
}

__global__ void k_scatter(const int* __restrict__ src, const int* __restrict__ dst,
                          const int* __restrict__ row_start, int* __restrict__ cur,
                          int* __restrict__ csr, int E) {
    int i = blockIdx.x * blockDim.x + threadIdx.x;
    int stride = gridDim.x * blockDim.x;
    for (; i < E; i += stride) {
        int d = dst[i];
        int p = atomicAdd(&cur[d], 1);
        csr[row_start[d] + p] = src[i];
    }
}

__global__ void k_gstart(const int* __restrict__ batch, int* __restrict__ gs,
                         int n, int G) {
    int g = blockIdx.x * blockDim.x + threadIdx.x;
    if (g > G) return;
    if (g == G) { gs[G] = n; return; }
    int lo = 0, hi = n;
    while (lo < hi) {
        int mid = (lo + hi) >> 1;
        if (batch[mid] < g) lo = mid + 1; else hi = mid;
    }
    gs[g] = lo;
}

// weight transpose: Wt[l][j][k] = W[l][k][j]  (lane j's column contiguous)
__global__ void k_wt(const float* __restrict__ W, float* __restrict__ Wt, int total) {
    int i = blockIdx.x * blockDim.x + threadIdx.x;
    if (i >= total) return;
    int l = i >> 12, r = i & 4095, j = r >> 6, k = r & 63;
    Wt[(l << 12) + (j << 6) + k] = W[(l << 12) + (k << 6) + j];
}

// ------ gather: agg[n] = x[n] + sum neighbors; 4 rows per load instr --------

__global__ __launch_bounds__(256, 4) void k_gather(
    const float* __restrict__ x, const int* __restrict__ row_start,
    const int* __restrict__ csr, float* __restrict__ agg, int n)
{
    int lane = threadIdx.x & 63;
    int g = lane >> 4;            // row group 0..3
    int c16 = lane & 15;          // 16-lane column within group (4 dims each)
    int wid = (blockIdx.x * blockDim.x + threadIdx.x) >> 6;
    int nw = (gridDim.x * blockDim.x) >> 6;

    for (int node = wid; node < n; node += nw) {
        int s0 = row_start[node], s1 = row_start[node + 1];
        // init: only group 0 carries x[node] (avoid 4x counting)
        float4 x4 = *(const float4*)&x[(size_t)node * 64 + c16 * 4];
        float4 acc;
        acc.x = g == 0 ? x4.x : 0.f;
        acc.y = g == 0 ? x4.y : 0.f;
        acc.z = g == 0 ? x4.z : 0.f;
        acc.w = g == 0 ? x4.w : 0.f;

        int j = s0;
        for (; j + 16 <= s1; j += 16) {
            // group g, slot u -> row position g+4u; 16-lane broadcast index read
            int i0 = csr[j + g + 0];
            int i1 = csr[j + g + 4];
            int i2 = csr[j + g + 8];
            int i3 = csr[j + g + 12];
            float4 a0 = *(const float4*)&x[(size_t)i0 * 64 + c16 * 4];
            float4 a1 = *(const float4*)&x[(size_t)i1 * 64 + c16 * 4];
            float4 a2 = *(const float4*)&x[(size_t)i2 * 64 + c16 * 4];
            float4 a3 = *(const float4*)&x[(size_t)i3 * 64 + c16 * 4];
            acc.x += (a0.x + a1.x) + (a2.x + a3.x);
            acc.y += (a0.y + a1.y) + (a2.y + a3.y);
            acc.z += (a0.z + a1.z) + (a2.z + a3.z);
            acc.w += (a0.w + a1.w) + (a2.w + a3.w);
        }
        int cnt = s1 - j;                       // tail < 16
        if (cnt) {
#pragma unroll
            for (int u = 0; u < 4; ++u) {
                int p = g + 4 * u;              // uniform within group
                int idx = csr[j + (p < cnt ? p : 0)];
                float4 a = *(const float4*)&x[(size_t)idx * 64 + c16 * 4];
                if (p < cnt) {
                    acc.x += a.x; acc.y += a.y; acc.z += a.z; acc.w += a.w;
                }
            }
        }
        // cross-group reduce (groups differ in bits 4,5 of lane)
        acc.x += __shfl_xor(acc.x, 16); acc.y += __shfl_xor(acc.y, 16);
        acc.z += __shfl_xor(acc.z, 16); acc.w += __shfl_xor(acc.w, 16);
        acc.x += __shfl_xor(acc.x, 32); acc.y += __shfl_xor(acc.y, 32);
        acc.z += __shfl_xor(acc.z, 32); acc.w += __shfl_xor(acc.w, 32);
        if (lane < 16)
            *(float4*)&agg[(size_t)node * 64 + c16 * 4] = acc;
    }
}

// --- wave-per-graph: MLP (weights in VGPR) + fused pooling, in-place on xb ---

__global__ __launch_bounds__(256, 2) void k_gemm_pool(
    float* __restrict__ xb,                       // in: agg, out: layer output
    const int* __restrict__ gs,
    const float* __restrict__ Wt1, const float* __restrict__ b1,
    const float* __restrict__ gamma, const float* __restrict__ beta,
    const float* __restrict__ mean, const float* __restrict__ var,
    const float* __restrict__ Wt2, const float* __restrict__ b2,
    float* __restrict__ pooled, int G, int lay, int lh)
{
    int lane = threadIdx.x & 63;
    int wid = (blockIdx.x * blockDim.x + threadIdx.x) >> 6;
    if (wid >= G) return;

    // lane's output column of W1/W2: 16+16 contiguous float4 loads, pinned
    float4 w1v[16], w2v[16];
    const float4* W1p = (const float4*)Wt1 + (size_t)lane * 16;
    const float4* W2p = (const float4*)Wt2 + (size_t)lane * 16;
#pragma unroll
    for (int q = 0; q < 16; ++q) w1v[q] = W1p[q];
#pragma unroll
    for (int q = 0; q < 16; ++q) w2v[q] = W2p[q];
#pragma unroll
    for (int q = 0; q < 16; ++q) {
        asm volatile("" : "+v"(w1v[q].x), "+v"(w1v[q].y), "+v"(w1v[q].z), "+v"(w1v[q].w));
        asm volatile("" : "+v"(w2v[q].x), "+v"(w2v[q].y), "+v"(w2v[q].z), "+v"(w2v[q].w));
    }

    float bias1 = b1[lane];
    float sc = gamma[lane] * rsqrtf(var[lane] + 1e-5f);
    float sh = beta[lane] - mean[lane] * sc;
    float bias2 = b2[lane];

    int s0 = gs[wid], s1 = gs[wid + 1];
    int g4 = lane >> 4, c16 = lane & 15;
    float pacc = 0.f;

    for (int nb = s0; nb < s1; nb += 4) {
        // one 1KB load: group g4 holds row nb+g4 (clamped), dims c16*4..+3
        int rowc = nb + g4; if (rowc > s1 - 1) rowc = s1 - 1;
        float4 a4 = *(const float4*)&xb[(size_t)rowc * 64 + c16 * 4];

#pragma unroll
        for (int r = 0; r < 4; ++r) {
            if (nb + r >= s1) break;
            // GEMM1: broadcast node r's dim k=4q+c from lane r*16+q, comp c
            float h0 = bias1, h1 = 0.f, h2 = 0.f, h3 = 0.f;
#pragma unroll
            for (int q = 0; q < 16; ++q) {
                h0 += rlf(a4.x, r * 16 + q) * w1v[q].x;
                h1 += rlf(a4.y, r * 16 + q) * w1v[q].y;
                h2 += rlf(a4.z, r * 16 + q) * w1v[q].z;
                h3 += rlf(a4.w, r * 16 + q) * w1v[q].w;
            }
            float h = fmaxf(((h0 + h1) + (h2 + h3)) * sc + sh, 0.f);
            // GEMM2: standard lane-dim broadcast
            float o0 = bias2, o1 = 0.f, o2 = 0.f, o3 = 0.f;
#pragma unroll
            for (int q = 0; q < 16; ++q) {
                o0 += rlf(h, 4 * q + 0) * w2v[q].x;
                o1 += rlf(h, 4 * q + 1) * w2v[q].y;
                o2 += rlf(h, 4 * q + 2) * w2v[q].z;
                o3 += rlf(h, 4 * q + 3) * w2v[q].w;
            }
            float o = fmaxf((o0 + o1) + (o2 + o3), 0.f);
            xb[(size_t)(nb + r) * 64 + lane] = o;
            pacc += o;
        }
    }
    pooled[(size_t)wid * lh + lay * 64 + lane] = pacc;
}

// ---------------- FC head ----------------

__global__ __launch_bounds__(256) void k_fc(
    const float* __restrict__ pooled, const int* __restrict__ acid,
    const float* __restrict__ conc, const float* __restrict__ emb_acid,
    const float* __restrict__ emb_conc, const float* __restrict__ fc1W,
    const float* __restrict__ fc1b, const float* __restrict__ fc2W,
    const float* __restrict__ fc2b, float* __restrict__ out, int G, int lh)
{
    __shared__ float sf[4][448];
    int lane = threadIdx.x & 63;
    int w = threadIdx.x >> 6;
    int g = blockIdx.x * 4 + w;
    int fcin = lh + 256;
    if (g < G) {
        const float* pr = pooled + (size_t)g * lh;
        for (int c = lane; c < lh; c += 64) sf[w][c] = pr[c];
        const float* ea = emb_acid + acid[g] * 128;
        int ci = (conc[g] == 0.5f) ? 0 : 1;
        const float* ec = emb_conc + ci * 128;
        sf[w][lh + lane] = ea[lane];
        sf[w][lh + 64 + lane] = ea[lane + 64];
        sf[w][lh + 128 + lane] = ec[lane];
        sf[w][lh + 192 + lane] = ec[lane + 64];
    }
    __syncthreads();
    if (g >= G) return;
    float h0 = fc1b[lane], h1 = 0.f;
    for (int k = 0; k + 2 <= fcin; k += 2) {
        h0 += sf[w][k] * fc1W[(size_t)k * 64 + lane];
        h1 += sf[w][k + 1] * fc1W[(size_t)(k + 1) * 64 + lane];
    }
    float h = fmaxf(h0 + h1, 0.f);
    float p0 = h * fc2W[lane * 2 + 0];
    float p1 = h * fc2W[lane * 2 + 1];
    for (int off = 32; off; off >>= 1) {
        p0 += __shfl_xor(p0, off, 64);
        p1 += __shfl_xor(p1, off, 64);
    }
    if (lane == 0) {
        out[g * 2 + 0] = 1.0f / (1.0f + expf(-(p0 + fc2b[0])));
        out[g * 2 + 1] = 1.0f / (1.0f + expf(-(p1 + fc2b[1])));
    }
}

// ---------------- launch ----------------

extern "C" void kernel_launch(void* const* d_in, const int* in_sizes, int n_in,
                              void* d_out, int out_size, void* d_ws, size_t ws_size,
                              hipStream_t stream)
{
    const float* x_a      = (const float*)d_in[0];
    const int*   ei       = (const int*)d_in[1];
    const int*   batch    = (const int*)d_in[2];
    const int*   acid     = (const int*)d_in[3];
    const float* conc     = (const float*)d_in[4];
    const float* W1s      = (const float*)d_in[6];
    const float* b1s      = (const float*)d_in[7];
    const float* gammas   = (const float*)d_in[8];
    const float* betas    = (const float*)d_in[9];
    const float* bn_means = (const float*)d_in[10];
    const float* bn_vars  = (const float*)d_in[11];
    const float* W2s      = (const float*)d_in[12];
    const float* b2s      = (const float*)d_in[13];
    const float* emb_acid = (const float*)d_in[14];
    const float* emb_conc = (const float*)d_in[15];
    const float* fc1W     = (const float*)d_in[16];
    const float* fc1b     = (const float*)d_in[17];
    const float* fc2W     = (const float*)d_in[18];
    const float* fc2b     = (const float*)d_in[19];

    const int N = in_sizes[0] / 64;
    const int E = in_sizes[1] / 2;
    const int G = in_sizes[3];
    const int L = in_sizes[6] / (64 * 64);
    const int LH = 64 * L;

    char* ws = (char*)d_ws;
    size_t off = 0;
    auto alloc = [&](size_t bytes) -> void* {
        void* p = ws + off;
        off += (bytes + 255) & ~(size_t)255;
        return p;
    };
    float* buf0      = (float*)alloc(((size_t)N + 8) * 64 * 4);
    float* buf1      = (float*)alloc(((size_t)N + 8) * 64 * 4);
    float* pooled    = (float*)alloc((size_t)G * LH * 4);
    int*   row_start = (int*)alloc((size_t)(N + 1) * 4);
    int*   deg       = (int*)alloc((size_t)N * 4);      // reused as cursor
    int*   csr       = (int*)alloc((size_t)E * 4);
    int*   bsum      = (int*)alloc(4096);
    int*   gs        = (int*)alloc((size_t)(G + 1) * 4);
    float* Wt1       = (float*)alloc((size_t)L * 4096 * 4);
    float* Wt2       = (float*)alloc((size_t)L * 4096 * 4);

    const int* srcv = ei;
    const int* dstv = ei + E;

    // CSR build (reused by all layers)
    hipMemsetAsync(deg, 0, (size_t)N * 4, stream);
    k_hist<<<4096, 256, 0, stream>>>(dstv, deg, E);
    int nb = (N + SCAN_B - 1) / SCAN_B;
    k_scan1<<<nb, SCAN_B, 0, stream>>>(deg, row_start, bsum, N);
    k_scan2<<<1, SCAN_B, 0, stream>>>(bsum, nb);
    k_scan3<<<nb, SCAN_B, 0, stream>>>(row_start, bsum, N, E);
    hipMemsetAsync(deg, 0, (size_t)N * 4, stream);
    k_scatter<<<4096, 256, 0, stream>>>(srcv, dstv, row_start, deg, csr, E);
    k_gstart<<<(G + 256) / 256, 256, 0, stream>>>(batch, gs, N, G);

    // weight transposes (lane-major columns)
    int wtot = L * 4096;
    k_wt<<<(wtot + 255) / 256, 256, 0, stream>>>(W1s, Wt1, wtot);
    k_wt<<<(wtot + 255) / 256, 256, 0, stream>>>(W2s, Wt2, wtot);

    // GIN layers: gather -> wave-per-graph MLP + fused pool
    const float* xin = x_a;
    float* bufs[2] = {buf0, buf1};
    for (int l = 0; l < L; ++l) {
        float* xb = bufs[l & 1];
        k_gather<<<4096, 256, 0, stream>>>(xin, row_start, csr, xb, N);
        k_gemm_pool<<<(G + 3) / 4, 256, 0, stream>>>(
            xb, gs,
            Wt1 + (size_t)l * 4096, b1s + l * 64,
            gammas + l * 64, betas + l * 64,
            bn_means + l * 64, bn_vars + l * 64,
            Wt2 + (size_t)l * 4096, b2s + l * 64,
            pooled, G, l, LH);
        xin = xb;
    }

    // FC head
    k_fc<<<(G + 3) / 4, 256, 0, stream>>>(pooled, acid, conc, emb_acid, emb_conc,
                                          fc1W, fc1b, fc2W, fc2b,
                                          (float*)d_out, G, LH);
}